// Round 9
// baseline (181.152 us; speedup 1.0000x reference)
//
#include <hip/hip_runtime.h>
#include <hip/hip_bf16.h>
#include <math.h>

#define BTOT 16384

typedef __attribute__((ext_vector_type(8))) short short8;
typedef __attribute__((ext_vector_type(4))) float f32x4;
typedef __attribute__((ext_vector_type(16))) float f32x16;

__device__ __forceinline__ float selu_f(float x) {
  const float scale = 1.0507009873554805f;
  const float alpha = 1.6732632423543772f;
  return scale * (x > 0.0f ? x : alpha * expm1f(x));
}

// ---------------- prep: p -> bf16 ----------------
__global__ __launch_bounds__(256) void convert_p_kernel(
    const float* __restrict__ p, __hip_bfloat16* __restrict__ out) {
  int i = (blockIdx.x * 256 + threadIdx.x) * 4;
  float4 v = *reinterpret_cast<const float4*>(p + i);
  out[i + 0] = __float2bfloat16(v.x);
  out[i + 1] = __float2bfloat16(v.y);
  out[i + 2] = __float2bfloat16(v.z);
  out[i + 3] = __float2bfloat16(v.w);
}

// ---------------- prep: W[K][N] f32 -> Wt[N][K] bf16 (t-row excluded) ---------
__global__ __launch_bounds__(256) void transpose_w_kernel(
    const float* __restrict__ W, __hip_bfloat16* __restrict__ Wt, int K, int N) {
  __shared__ float tile[32][33];
  const int kb = blockIdx.x * 32, nb = blockIdx.y * 32;
  const int tx = threadIdx.x & 31, ty = threadIdx.x >> 5;
  #pragma unroll
  for (int rr = 0; rr < 4; ++rr) {
    int kl = ty + rr * 8;
    tile[kl][tx] = W[(size_t)(kb + kl) * N + nb + tx];
  }
  __syncthreads();
  #pragma unroll
  for (int rr = 0; rr < 4; ++rr) {
    int nl = ty + rr * 8;
    Wt[(size_t)(nb + nl) * K + kb + tx] = __float2bfloat16(tile[tx][nl]);
  }
}

// ---------------- MFMA MLP layer, 128x128 tile (layer 0 only, K=32) ----------
template<int BK, int MODE>
__global__ __launch_bounds__(256) void mlp_mfma_kernel(
    const __hip_bfloat16* __restrict__ X, int ldx, int Kc,
    const float* __restrict__ tvec,
    const __hip_bfloat16* __restrict__ Wt,
    const float* __restrict__ Wlast,
    const float* __restrict__ bias,
    __hip_bfloat16* __restrict__ Yout, int ldy) {
  constexpr int NBLK = BK / 8;
  constexpr int AB = 128 * BK * 2;
  constexpr int IPW = AB / 1024 / 4;
  __shared__ char lds[4 * AB];
  const int tid = threadIdx.x;
  const int w = tid >> 6, lane = tid & 63;
  const int wr = w >> 1, wc = w & 1;
  const int rowbase = blockIdx.x * 128, colbase = blockIdx.y * 128;

  const __hip_bfloat16* srcA[IPW];
  const __hip_bfloat16* srcB[IPW];
  int ldsoff[IPW];
  #pragma unroll
  for (int i = 0; i < IPW; ++i) {
    int f = (w * IPW + i) * 64 + lane;
    int r = f / NBLK, slot = f % NBLK;
    int kb = slot ^ (r & (NBLK - 1));
    srcA[i] = X + (size_t)(rowbase + r) * ldx + kb * 8;
    srcB[i] = Wt + (size_t)(colbase + r) * Kc + kb * 8;
    ldsoff[i] = (w * IPW + i) * 1024;
  }

  f32x4 acc[4][4] = {};

  int aoff[4], amask[4], boff[4], bmask[4];
  #pragma unroll
  for (int i = 0; i < 4; ++i) {
    int ra = wr * 64 + i * 16 + (lane & 15);
    aoff[i] = ra * BK * 2;
    amask[i] = ra & (NBLK - 1);
    int cb = wc * 64 + i * 16 + (lane & 15);
    boff[i] = cb * BK * 2;
    bmask[i] = cb & (NBLK - 1);
  }
  const int kgrp = lane >> 4;

  auto stage_tile = [&](int buf, int t) {
    char* ab = lds + buf * 2 * AB;
    #pragma unroll
    for (int i = 0; i < IPW; ++i) {
      __builtin_amdgcn_global_load_lds(
          (const __attribute__((address_space(1))) void*)(srcA[i] + t * BK),
          (__attribute__((address_space(3))) void*)(ab + ldsoff[i]), 16, 0, 0);
      __builtin_amdgcn_global_load_lds(
          (const __attribute__((address_space(1))) void*)(srcB[i] + t * BK),
          (__attribute__((address_space(3))) void*)(ab + AB + ldsoff[i]), 16, 0, 0);
    }
  };

  auto compute_tile = [&](int buf) {
    const char* Abse = lds + buf * 2 * AB;
    const char* Bbse = Abse + AB;
    #pragma unroll
    for (int kh = 0; kh < BK / 32; ++kh) {
      short8 a[4], b[4];
      const int kb = kh * 4 + kgrp;
      #pragma unroll
      for (int i = 0; i < 4; ++i) {
        a[i] = *reinterpret_cast<const short8*>(Abse + aoff[i] + ((kb ^ amask[i]) * 16));
        b[i] = *reinterpret_cast<const short8*>(Bbse + boff[i] + ((kb ^ bmask[i]) * 16));
      }
      #pragma unroll
      for (int i = 0; i < 4; ++i)
        #pragma unroll
        for (int j = 0; j < 4; ++j)
          acc[i][j] = __builtin_amdgcn_mfma_f32_16x16x32_bf16(a[i], b[j], acc[i][j], 0, 0, 0);
    }
  };

  const int nt = Kc / BK;
  stage_tile(0, 0);
  asm volatile("s_waitcnt vmcnt(0)" ::: "memory");
  __syncthreads();
  int buf = 0;
  #pragma unroll 1
  for (int t = 0; t < nt - 1; ++t) {
    stage_tile(buf ^ 1, t + 1);
    compute_tile(buf);
    asm volatile("s_waitcnt vmcnt(0)" ::: "memory");
    __syncthreads();
    buf ^= 1;
  }
  compute_tile(buf);

  const int colloc = lane & 15;
  const int rowgrp = lane >> 4;
  float wl[4], bb[4];
  #pragma unroll
  for (int j = 0; j < 4; ++j) {
    int col = colbase + wc * 64 + j * 16 + colloc;
    wl[j] = Wlast[col];
    bb[j] = bias[col];
  }
  #pragma unroll
  for (int i = 0; i < 4; ++i) {
    #pragma unroll
    for (int e = 0; e < 4; ++e) {
      int row = rowbase + wr * 64 + i * 16 + rowgrp * 4 + e;
      float tv = tvec[row];
      #pragma unroll
      for (int j = 0; j < 4; ++j) {
        float v = acc[i][j][e] + tv * wl[j] + bb[j];
        if (MODE == 0) v = selu_f(v);
        else           v = fminf(fmaxf(v, -20.f), 20.f);
        int col = colbase + wc * 64 + j * 16 + colloc;
        Yout[(size_t)row * ldy + col] = __float2bfloat16(v);
      }
    }
  }
}

// ---------------- MFMA MLP wide layer: 64 rows x 512 cols per block ----------
// K=512. Grid (M/64, Ntot/512). 512 threads = 8 waves (2M x 4N), wave tile
// 32x128 (acc 2x8 frags). BK=32, double-buffered. X read ONCE from HBM; Wt
// slab (0.5 MB per col-half) stays L2-resident across blocks.
template<int MODE>
__global__ __launch_bounds__(512) void mlp_wide_kernel(
    const __hip_bfloat16* __restrict__ X, int ldx,
    const float* __restrict__ tvec,
    const __hip_bfloat16* __restrict__ Wt,    // [Ntot][512] bf16
    const float* __restrict__ Wlast,          // t-row, fp32 [Ntot]
    const float* __restrict__ bias,           // fp32 [Ntot]
    __hip_bfloat16* __restrict__ Yout, int ldy) {
  constexpr int Kc = 512, BK = 32;
  constexpr int ABYTES = 64 * BK * 2;          // 4 KB
  constexpr int BBYTES = 512 * BK * 2;         // 32 KB
  constexpr int BUF = ABYTES + BBYTES;         // 36 KB
  __shared__ char lds[2 * BUF];
  const int tid = threadIdx.x;
  const int w = tid >> 6, lane = tid & 63;
  const int wm = w >> 2, wn = w & 3;
  const int rowbase = blockIdx.x * 64;
  const int noff = blockIdx.y * 512;
  const __hip_bfloat16* WtB = Wt + (size_t)noff * Kc;

  // staging sources (pre-swizzled kb, linear LDS dest)
  const __hip_bfloat16* srcA = X;
  int ldsoffA = 0;
  if (w < 4) {
    int fa = w * 64 + lane;                 // 256 16B-blocks of A (64 rows x 4)
    int r = fa >> 2, slot = fa & 3;
    int kb = slot ^ (r & 3);
    srcA = X + (size_t)(rowbase + r) * ldx + kb * 8;
    ldsoffA = fa * 16;
  }
  const __hip_bfloat16* srcB[4];
  int ldsoffB[4];
  #pragma unroll
  for (int i = 0; i < 4; ++i) {
    int fb = (w * 4 + i) * 64 + lane;       // 2048 16B-blocks of B (512 x 4)
    int n = fb >> 2, slot = fb & 3;
    int kb = slot ^ (n & 3);
    srcB[i] = WtB + (size_t)n * Kc + kb * 8;
    ldsoffB[i] = ABYTES + fb * 16;
  }

  f32x4 acc[2][8] = {};
  int aoff[2], amask[2], boff[8], bmask[8];
  #pragma unroll
  for (int i = 0; i < 2; ++i) {
    int ra = wm * 32 + i * 16 + (lane & 15);
    aoff[i] = ra * (BK * 2);
    amask[i] = ra & 3;
  }
  #pragma unroll
  for (int j = 0; j < 8; ++j) {
    int cb = wn * 128 + j * 16 + (lane & 15);
    boff[j] = cb * (BK * 2);
    bmask[j] = cb & 3;
  }
  const int kgrp = lane >> 4;

  auto stage = [&](int buf, int t) {
    char* bb_ = lds + buf * BUF;
    if (w < 4)
      __builtin_amdgcn_global_load_lds(
          (const __attribute__((address_space(1))) void*)(srcA + t * BK),
          (__attribute__((address_space(3))) void*)(bb_ + ldsoffA), 16, 0, 0);
    #pragma unroll
    for (int i = 0; i < 4; ++i)
      __builtin_amdgcn_global_load_lds(
          (const __attribute__((address_space(1))) void*)(srcB[i] + t * BK),
          (__attribute__((address_space(3))) void*)(bb_ + ldsoffB[i]), 16, 0, 0);
  };

  auto compute = [&](int buf) {
    const char* Ab = lds + buf * BUF;
    const char* Bb = Ab + ABYTES;
    short8 a[2], b[8];
    #pragma unroll
    for (int i = 0; i < 2; ++i)
      a[i] = *reinterpret_cast<const short8*>(Ab + aoff[i] + ((kgrp ^ amask[i]) * 16));
    #pragma unroll
    for (int j = 0; j < 8; ++j)
      b[j] = *reinterpret_cast<const short8*>(Bb + boff[j] + ((kgrp ^ bmask[j]) * 16));
    #pragma unroll
    for (int i = 0; i < 2; ++i)
      #pragma unroll
      for (int j = 0; j < 8; ++j)
        acc[i][j] = __builtin_amdgcn_mfma_f32_16x16x32_bf16(a[i], b[j], acc[i][j], 0, 0, 0);
  };

  stage(0, 0);
  asm volatile("s_waitcnt vmcnt(0)" ::: "memory");
  __syncthreads();
  int buf = 0;
  #pragma unroll 1
  for (int t = 0; t < Kc / BK - 1; ++t) {
    stage(buf ^ 1, t + 1);
    compute(buf);
    asm volatile("s_waitcnt vmcnt(0)" ::: "memory");
    __syncthreads();
    buf ^= 1;
  }
  compute(buf);

  // epilogue
  const int colloc = lane & 15, rowgrp = lane >> 4;
  float wl[8], bb2[8];
  #pragma unroll
  for (int j = 0; j < 8; ++j) {
    int col = noff + wn * 128 + j * 16 + colloc;
    wl[j] = Wlast[col];
    bb2[j] = bias[col];
  }
  #pragma unroll
  for (int i = 0; i < 2; ++i) {
    #pragma unroll
    for (int e = 0; e < 4; ++e) {
      int row = rowbase + wm * 32 + i * 16 + rowgrp * 4 + e;
      float tv = tvec[row];
      #pragma unroll
      for (int j = 0; j < 8; ++j) {
        float v = acc[i][j][e] + tv * wl[j] + bb2[j];
        v = (MODE == 0) ? selu_f(v) : fminf(fmaxf(v, -20.f), 20.f);
        Yout[(size_t)row * ldy + noff + wn * 128 + j * 16 + colloc] = __float2bfloat16(v);
      }
    }
  }
}

// ---------------- expm: transposed chain + MFMA matvec squaring (r8, passing) --
#define WAITLDS asm volatile("s_waitcnt lgkmcnt(0)" ::: "memory")

__device__ __forceinline__ unsigned int bf16r(float x) {
  return (__float_as_uint(x) + 0x8000u) >> 16;
}

__device__ __forceinline__ void d2b(const float (&X)[16], int G, short8 (&bfr)[2]) {
  float oth[16];
  #pragma unroll
  for (int i = 0; i < 16; ++i) oth[i] = __shfl_xor(X[i], 32);
  #pragma unroll
  for (int h = 0; h < 2; ++h) {
    float r8[8];
    #pragma unroll
    for (int j2 = 0; j2 < 8; ++j2) {
      float g0 = (j2 < 4) ? X[8 * h + j2] : oth[8 * h + j2 - 4];
      float g1 = (j2 < 4) ? oth[8 * h + 4 + j2] : X[8 * h + j2];
      r8[j2] = G ? g1 : g0;
    }
    union { short8 s8; unsigned int u[4]; } bu;
    #pragma unroll
    for (int j = 0; j < 4; ++j)
      bu.u[j] = bf16r(r8[2 * j]) | (bf16r(r8[2 * j + 1]) << 16);
    bfr[h] = bu.s8;
  }
}

__device__ __forceinline__ void d2b_split(const float (&X)[16], int G,
                                          short8 (&bh)[2], short8 (&bl)[2]) {
  float oth[16];
  #pragma unroll
  for (int i = 0; i < 16; ++i) oth[i] = __shfl_xor(X[i], 32);
  #pragma unroll
  for (int h = 0; h < 2; ++h) {
    float r8[8];
    #pragma unroll
    for (int j2 = 0; j2 < 8; ++j2) {
      float g0 = (j2 < 4) ? X[8 * h + j2] : oth[8 * h + j2 - 4];
      float g1 = (j2 < 4) ? oth[8 * h + 4 + j2] : X[8 * h + j2];
      r8[j2] = G ? g1 : g0;
    }
    union { short8 s8; unsigned int u[4]; } uh, ul;
    #pragma unroll
    for (int j = 0; j < 4; ++j) {
      unsigned int b0 = __float_as_uint(r8[2 * j]) & 0xFFFF0000u;
      unsigned int b1 = __float_as_uint(r8[2 * j + 1]) & 0xFFFF0000u;
      float l0 = r8[2 * j] - __uint_as_float(b0);
      float l1 = r8[2 * j + 1] - __uint_as_float(b1);
      uh.u[j] = (b0 >> 16) | b1;
      ul.u[j] = bf16r(l0) | (bf16r(l1) << 16);
    }
    bh[h] = uh.s8;
    bl[h] = ul.s8;
  }
}

__global__ __launch_bounds__(256) void expm_tchain_kernel(
    const __hip_bfloat16* __restrict__ flat,
    const float* __restrict__ q,
    const float* __restrict__ dtp,
    float* __restrict__ out_q,
    float* __restrict__ out_dlogp) {
  __shared__ __align__(16) unsigned int SL[4][16][33];
  const int tid = threadIdx.x;
  const int w = tid >> 6, lane = tid & 63;
  const int C = lane & 31, G = lane >> 5;
  const int m = blockIdx.x * 4 + w;
  const float dt = dtp[0];

  const uint4* fm = reinterpret_cast<const uint4*>(flat + (size_t)m * 1024);
  uint4 v0 = fm[lane];
  uint4 v1 = fm[lane + 64];
  {
    const int r0 = lane >> 2, kpb = (lane & 3) * 4;
    SL[w][kpb + 0][r0] = v0.x; SL[w][kpb + 1][r0] = v0.y;
    SL[w][kpb + 2][r0] = v0.z; SL[w][kpb + 3][r0] = v0.w;
    SL[w][kpb + 0][r0 + 16] = v1.x; SL[w][kpb + 1][r0 + 16] = v1.y;
    SL[w][kpb + 2][r0 + 16] = v1.z; SL[w][kpb + 3][r0 + 16] = v1.w;
  }

  union u4s8 { uint4 u4; short8 s8; unsigned int u[4]; };
  u4s8 t0, t1;
  {
    const char* base = reinterpret_cast<const char*>(flat) + (size_t)m * 2048 + C * 64 + G * 16;
    t0.u4 = *reinterpret_cast<const uint4*>(base);
    t1.u4 = *reinterpret_cast<const uint4*>(base + 32);
  }

  float sa = 0.f;
  {
    unsigned int a0[4] = {t0.u[0], t0.u[1], t0.u[2], t0.u[3]};
    unsigned int a1[4] = {t1.u[0], t1.u[1], t1.u[2], t1.u[3]};
    #pragma unroll
    for (int i = 0; i < 4; ++i) {
      sa += fabsf(__uint_as_float(a0[i] << 16)) + fabsf(__uint_as_float(a0[i] & 0xFFFF0000u));
      sa += fabsf(__uint_as_float(a1[i] << 16)) + fabsf(__uint_as_float(a1[i] & 0xFFFF0000u));
    }
  }
  sa += __shfl_xor(sa, 32);
  float nrm = sa;
  #pragma unroll
  for (int off = 1; off < 32; off <<= 1) nrm = fmaxf(nrm, __shfl_xor(nrm, off));

  int s = 0;
  float anrm = dt * nrm;
  if (anrm > 1.5f) {
    s = (int)ceilf(log2f(anrm * (1.0f / 1.5f)));
    s = s < 1 ? 1 : (s > 6 ? 6 : s);
  }
  const float u = dt * exp2f(-(float)s);

  unsigned int pt0[4], pt1[4];
  #pragma unroll
  for (int d = 0; d < 4; ++d) {
    pt0[d] = (unsigned int)__shfl_xor((int)t0.u[d], 32);
    pt1[d] = (unsigned int)__shfl_xor((int)t1.u[d], 32);
  }
  float E[16], dIa[16];
  float tr = 0.f;
  #pragma unroll
  for (int j = 0; j < 4; ++j) {
    #pragma unroll
    for (int e2 = 0; e2 < 4; ++e2) {
      const int i = 4 * j + e2;
      const int rd = e2 + 8 * j + 4 * G;
      const bool own = ((j & 1) == G);
      unsigned int dwO, dwP;
      if ((e2 >> 1) == 0) {
        dwO = G ? ((j < 2) ? t0.u[2] : t1.u[2]) : ((j < 2) ? t0.u[0] : t1.u[0]);
        dwP = G ? ((j < 2) ? pt0[2] : pt1[2]) : ((j < 2) ? pt0[0] : pt1[0]);
      } else {
        dwO = G ? ((j < 2) ? t0.u[3] : t1.u[3]) : ((j < 2) ? t0.u[1] : t1.u[1]);
        dwP = G ? ((j < 2) ? pt0[3] : pt1[3]) : ((j < 2) ? pt0[1] : pt1[1]);
      }
      unsigned int dw = own ? dwO : dwP;
      unsigned int h16 = (e2 & 1) ? (dw >> 16) : (dw & 0xFFFFu);
      float mv = __uint_as_float(h16 << 16);
      float dI = (rd == C) ? 1.0f : 0.0f;
      dIa[i] = dI;
      E[i] = dI + u * mv;
      tr += dI * mv;
    }
  }
  #pragma unroll
  for (int off = 1; off < 64; off <<= 1) tr += __shfl_xor(tr, off);
  if (lane == 0) out_dlogp[m] = dt * tr;

  WAITLDS;

  short8 Mfr[2];
  {
    const unsigned int selpat = (C & 1) ? 0x07060302u : 0x05040100u;
    #pragma unroll
    for (int h = 0; h < 2; ++h) {
      unsigned int rr[8];
      #pragma unroll
      for (int e = 0; e < 8; ++e) rr[e] = SL[w][C >> 1][16 * h + 8 * G + e];
      union { short8 s8; unsigned int u[4]; } mu;
      #pragma unroll
      for (int j = 0; j < 4; ++j)
        mu.u[j] = __builtin_amdgcn_perm(rr[2 * j + 1], rr[2 * j], selpat);
      Mfr[h] = mu.s8;
    }
  }

  float Qc[16];
  float ck = u * u * 0.5f;
  {
    f32x16 acc = {};
    acc = __builtin_amdgcn_mfma_f32_32x32x16_bf16(Mfr[0], t0.s8, acc, 0, 0, 0);
    acc = __builtin_amdgcn_mfma_f32_32x32x16_bf16(Mfr[1], t1.s8, acc, 0, 0, 0);
    #pragma unroll
    for (int i = 0; i < 16; ++i) { Qc[i] = acc[i]; E[i] += ck * Qc[i]; }
  }
  #pragma unroll
  for (int k = 3; k <= 8; ++k) {
    short8 bfr[2];
    d2b(Qc, G, bfr);
    f32x16 acc = {};
    acc = __builtin_amdgcn_mfma_f32_32x32x16_bf16(Mfr[0], bfr[0], acc, 0, 0, 0);
    acc = __builtin_amdgcn_mfma_f32_32x32x16_bf16(Mfr[1], bfr[1], acc, 0, 0, 0);
    ck *= u * (1.0f / (float)k);
    #pragma unroll
    for (int i = 0; i < 16; ++i) { Qc[i] = acc[i]; E[i] += ck * Qc[i]; }
  }

  short8 beh[2], bel[2];
  d2b_split(E, G, beh, bel);

  float qv = q[(size_t)m * 32 + C];
  const int nv = 1 << s;
  #pragma unroll 1
  for (int it = 0; it < nv; ++it) {
    unsigned int hb = __float_as_uint(qv) & 0xFFFF0000u;
    float lof = qv - __uint_as_float(hb);
    unsigned int pw = (hb >> 16) | (bf16r(lof) << 16);
    short8 vh[2], vl[2];
    #pragma unroll
    for (int h = 0; h < 2; ++h) {
      unsigned int g[8];
      #pragma unroll
      for (int e = 0; e < 8; ++e)
        g[e] = (unsigned int)__shfl((int)pw, 16 * h + 8 * G + e);
      union { short8 s8; unsigned int u[4]; } uh, ul;
      #pragma unroll
      for (int j = 0; j < 4; ++j) {
        uh.u[j] = __builtin_amdgcn_perm(g[2 * j + 1], g[2 * j], 0x05040100u);
        ul.u[j] = __builtin_amdgcn_perm(g[2 * j + 1], g[2 * j], 0x07060302u);
      }
      vh[h] = uh.s8;
      vl[h] = ul.s8;
    }
    f32x16 acc = {};
    acc = __builtin_amdgcn_mfma_f32_32x32x16_bf16(vh[0], beh[0], acc, 0, 0, 0);
    acc = __builtin_amdgcn_mfma_f32_32x32x16_bf16(vh[1], beh[1], acc, 0, 0, 0);
    acc = __builtin_amdgcn_mfma_f32_32x32x16_bf16(vl[0], beh[0], acc, 0, 0, 0);
    acc = __builtin_amdgcn_mfma_f32_32x32x16_bf16(vl[1], beh[1], acc, 0, 0, 0);
    acc = __builtin_amdgcn_mfma_f32_32x32x16_bf16(vh[0], bel[0], acc, 0, 0, 0);
    acc = __builtin_amdgcn_mfma_f32_32x32x16_bf16(vh[1], bel[1], acc, 0, 0, 0);
    qv = acc[0];
  }
  if (G == 0) out_q[(size_t)m * 32 + C] = qv;
}

extern "C" void kernel_launch(void* const* d_in, const int* in_sizes, int n_in,
                              void* d_out, int out_size, void* d_ws, size_t ws_size,
                              hipStream_t stream) {
  const float* q    = (const float*)d_in[0];
  const float* p    = (const float*)d_in[1];
  const float* t    = (const float*)d_in[2];
  const float* dt   = (const float*)d_in[3];
  const float* W0   = (const float*)d_in[4];
  const float* b0   = (const float*)d_in[5];
  const float* W1   = (const float*)d_in[6];
  const float* b1   = (const float*)d_in[7];
  const float* W2   = (const float*)d_in[8];
  const float* b2   = (const float*)d_in[9];
  const float* W3   = (const float*)d_in[10];
  const float* b3   = (const float*)d_in[11];
  const float* Wout = (const float*)d_in[12];
  const float* bout = (const float*)d_in[13];

  // ws layout (all bf16 activations)
  __hip_bfloat16* flatb = (__hip_bfloat16*)d_ws;                 // B*1024
  __hip_bfloat16* act1  = flatb + (size_t)BTOT * 1024;           // B*512
  __hip_bfloat16* act2  = act1 + (size_t)BTOT * 512;             // B*512
  __hip_bfloat16* pbf   = act2 + (size_t)BTOT * 512;             // B*32
  __hip_bfloat16* Wt0   = pbf + (size_t)BTOT * 32;
  __hip_bfloat16* Wt1   = Wt0 + 512 * 32;
  __hip_bfloat16* Wt2   = Wt1 + 512 * 512;
  __hip_bfloat16* Wt3   = Wt2 + 512 * 512;
  __hip_bfloat16* WtO   = Wt3 + 512 * 512;

  dim3 blk(256);
  convert_p_kernel<<<BTOT * 32 / 1024, blk, 0, stream>>>(p, pbf);
  transpose_w_kernel<<<dim3(1, 16),  blk, 0, stream>>>(W0,   Wt0, 32,  512);
  transpose_w_kernel<<<dim3(16, 16), blk, 0, stream>>>(W1,   Wt1, 512, 512);
  transpose_w_kernel<<<dim3(16, 16), blk, 0, stream>>>(W2,   Wt2, 512, 512);
  transpose_w_kernel<<<dim3(16, 16), blk, 0, stream>>>(W3,   Wt3, 512, 512);
  transpose_w_kernel<<<dim3(16, 32), blk, 0, stream>>>(Wout, WtO, 512, 1024);

  mlp_mfma_kernel<32, 0><<<dim3(128, 4), blk, 0, stream>>>(
      pbf, 32, 32, t, Wt0, W0 + 32 * 512, b0, act1, 512);

  dim3 wblk(512);
  mlp_wide_kernel<0><<<dim3(256, 1), wblk, 0, stream>>>(
      act1, 512, t, Wt1, W1 + 512 * 512, b1, act2, 512);
  mlp_wide_kernel<0><<<dim3(256, 1), wblk, 0, stream>>>(
      act2, 512, t, Wt2, W2 + 512 * 512, b2, act1, 512);
  mlp_wide_kernel<0><<<dim3(256, 1), wblk, 0, stream>>>(
      act1, 512, t, Wt3, W3 + 512 * 512, b3, act2, 512);
  mlp_wide_kernel<1><<<dim3(256, 2), wblk, 0, stream>>>(
      act2, 512, t, WtO, Wout + 512 * 1024, bout, flatb, 1024);

  float* out_q     = (float*)d_out;
  float* out_dlogp = out_q + (size_t)BTOT * 32;
  expm_tchain_kernel<<<BTOT / 4, blk, 0, stream>>>(flatb, q, dt, out_q, out_dlogp);
}

// Round 10
// 163.248 us; speedup vs baseline: 1.1097x; 1.1097x over previous
//
#include <hip/hip_runtime.h>
#include <hip/hip_bf16.h>
#include <math.h>

#define BTOT 16384

typedef __attribute__((ext_vector_type(8))) short short8;
typedef __attribute__((ext_vector_type(4))) float f32x4;
typedef __attribute__((ext_vector_type(16))) float f32x16;

__device__ __forceinline__ float selu_f(float x) {
  const float scale = 1.0507009873554805f;
  const float alpha = 1.6732632423543772f;
  return scale * (x > 0.0f ? x : alpha * expm1f(x));
}

// ---------------- prep: p -> bf16 ----------------
__global__ __launch_bounds__(256) void convert_p_kernel(
    const float* __restrict__ p, __hip_bfloat16* __restrict__ out) {
  int i = (blockIdx.x * 256 + threadIdx.x) * 4;
  float4 v = *reinterpret_cast<const float4*>(p + i);
  out[i + 0] = __float2bfloat16(v.x);
  out[i + 1] = __float2bfloat16(v.y);
  out[i + 2] = __float2bfloat16(v.z);
  out[i + 3] = __float2bfloat16(v.w);
}

// ---------------- prep: W[K][N] f32 -> Wt[N][K] bf16 (t-row excluded) ---------
__global__ __launch_bounds__(256) void transpose_w_kernel(
    const float* __restrict__ W, __hip_bfloat16* __restrict__ Wt, int K, int N) {
  __shared__ float tile[32][33];
  const int kb = blockIdx.x * 32, nb = blockIdx.y * 32;
  const int tx = threadIdx.x & 31, ty = threadIdx.x >> 5;
  #pragma unroll
  for (int rr = 0; rr < 4; ++rr) {
    int kl = ty + rr * 8;
    tile[kl][tx] = W[(size_t)(kb + kl) * N + nb + tx];
  }
  __syncthreads();
  #pragma unroll
  for (int rr = 0; rr < 4; ++rr) {
    int nl = ty + rr * 8;
    Wt[(size_t)(nb + nl) * K + kb + tx] = __float2bfloat16(tile[tx][nl]);
  }
}

// ---------------- MFMA MLP layer, 128x128 tile ----------------
// Grid: (bn, bm) with bn FASTEST so the 4 (8) consumers of each X row-panel
// are adjacent in dispatch order -> X panel L2-resident (r9 lesson: keep the
// 128x128/BK=64 structure, fix reuse via dispatch order, not tile shape).
// MODE 0: selu + bf16 store.  MODE 1: clip(+-20) + bf16 store (final layer).
template<int BK, int MODE>
__global__ __launch_bounds__(256) void mlp_mfma_kernel(
    const __hip_bfloat16* __restrict__ X, int ldx, int Kc,
    const float* __restrict__ tvec,
    const __hip_bfloat16* __restrict__ Wt,
    const float* __restrict__ Wlast,
    const float* __restrict__ bias,
    __hip_bfloat16* __restrict__ Yout, int ldy) {
  constexpr int NBLK = BK / 8;
  constexpr int AB = 128 * BK * 2;
  constexpr int IPW = AB / 1024 / 4;
  __shared__ char lds[4 * AB];
  const int tid = threadIdx.x;
  const int w = tid >> 6, lane = tid & 63;
  const int wr = w >> 1, wc = w & 1;
  const int rowbase = blockIdx.y * 128, colbase = blockIdx.x * 128;

  const __hip_bfloat16* srcA[IPW];
  const __hip_bfloat16* srcB[IPW];
  int ldsoff[IPW];
  #pragma unroll
  for (int i = 0; i < IPW; ++i) {
    int f = (w * IPW + i) * 64 + lane;
    int r = f / NBLK, slot = f % NBLK;
    int kb = slot ^ (r & (NBLK - 1));
    srcA[i] = X + (size_t)(rowbase + r) * ldx + kb * 8;
    srcB[i] = Wt + (size_t)(colbase + r) * Kc + kb * 8;
    ldsoff[i] = (w * IPW + i) * 1024;
  }

  f32x4 acc[4][4] = {};

  int aoff[4], amask[4], boff[4], bmask[4];
  #pragma unroll
  for (int i = 0; i < 4; ++i) {
    int ra = wr * 64 + i * 16 + (lane & 15);
    aoff[i] = ra * BK * 2;
    amask[i] = ra & (NBLK - 1);
    int cb = wc * 64 + i * 16 + (lane & 15);
    boff[i] = cb * BK * 2;
    bmask[i] = cb & (NBLK - 1);
  }
  const int kgrp = lane >> 4;

  auto stage_tile = [&](int buf, int t) {
    char* ab = lds + buf * 2 * AB;
    #pragma unroll
    for (int i = 0; i < IPW; ++i) {
      __builtin_amdgcn_global_load_lds(
          (const __attribute__((address_space(1))) void*)(srcA[i] + t * BK),
          (__attribute__((address_space(3))) void*)(ab + ldsoff[i]), 16, 0, 0);
      __builtin_amdgcn_global_load_lds(
          (const __attribute__((address_space(1))) void*)(srcB[i] + t * BK),
          (__attribute__((address_space(3))) void*)(ab + AB + ldsoff[i]), 16, 0, 0);
    }
  };

  auto compute_tile = [&](int buf) {
    const char* Abse = lds + buf * 2 * AB;
    const char* Bbse = Abse + AB;
    #pragma unroll
    for (int kh = 0; kh < BK / 32; ++kh) {
      short8 a[4], b[4];
      const int kb = kh * 4 + kgrp;
      #pragma unroll
      for (int i = 0; i < 4; ++i) {
        a[i] = *reinterpret_cast<const short8*>(Abse + aoff[i] + ((kb ^ amask[i]) * 16));
        b[i] = *reinterpret_cast<const short8*>(Bbse + boff[i] + ((kb ^ bmask[i]) * 16));
      }
      #pragma unroll
      for (int i = 0; i < 4; ++i)
        #pragma unroll
        for (int j = 0; j < 4; ++j)
          acc[i][j] = __builtin_amdgcn_mfma_f32_16x16x32_bf16(a[i], b[j], acc[i][j], 0, 0, 0);
    }
  };

  const int nt = Kc / BK;
  stage_tile(0, 0);
  asm volatile("s_waitcnt vmcnt(0)" ::: "memory");
  __syncthreads();
  int buf = 0;
  #pragma unroll 1
  for (int t = 0; t < nt - 1; ++t) {
    stage_tile(buf ^ 1, t + 1);
    compute_tile(buf);
    asm volatile("s_waitcnt vmcnt(0)" ::: "memory");
    __syncthreads();
    buf ^= 1;
  }
  compute_tile(buf);

  const int colloc = lane & 15;
  const int rowgrp = lane >> 4;
  float wl[4], bb[4];
  #pragma unroll
  for (int j = 0; j < 4; ++j) {
    int col = colbase + wc * 64 + j * 16 + colloc;
    wl[j] = Wlast[col];
    bb[j] = bias[col];
  }
  #pragma unroll
  for (int i = 0; i < 4; ++i) {
    #pragma unroll
    for (int e = 0; e < 4; ++e) {
      int row = rowbase + wr * 64 + i * 16 + rowgrp * 4 + e;
      float tv = tvec[row];
      #pragma unroll
      for (int j = 0; j < 4; ++j) {
        float v = acc[i][j][e] + tv * wl[j] + bb[j];
        if (MODE == 0) v = selu_f(v);
        else           v = fminf(fmaxf(v, -20.f), 20.f);
        int col = colbase + wc * 64 + j * 16 + colloc;
        Yout[(size_t)row * ldy + col] = __float2bfloat16(v);
      }
    }
  }
}

// ---------------- expm: transposed chain + MFMA matvec squaring (r8, passing) --
#define WAITLDS asm volatile("s_waitcnt lgkmcnt(0)" ::: "memory")

__device__ __forceinline__ unsigned int bf16r(float x) {
  return (__float_as_uint(x) + 0x8000u) >> 16;
}

__device__ __forceinline__ void d2b(const float (&X)[16], int G, short8 (&bfr)[2]) {
  float oth[16];
  #pragma unroll
  for (int i = 0; i < 16; ++i) oth[i] = __shfl_xor(X[i], 32);
  #pragma unroll
  for (int h = 0; h < 2; ++h) {
    float r8[8];
    #pragma unroll
    for (int j2 = 0; j2 < 8; ++j2) {
      float g0 = (j2 < 4) ? X[8 * h + j2] : oth[8 * h + j2 - 4];
      float g1 = (j2 < 4) ? oth[8 * h + 4 + j2] : X[8 * h + j2];
      r8[j2] = G ? g1 : g0;
    }
    union { short8 s8; unsigned int u[4]; } bu;
    #pragma unroll
    for (int j = 0; j < 4; ++j)
      bu.u[j] = bf16r(r8[2 * j]) | (bf16r(r8[2 * j + 1]) << 16);
    bfr[h] = bu.s8;
  }
}

__device__ __forceinline__ void d2b_split(const float (&X)[16], int G,
                                          short8 (&bh)[2], short8 (&bl)[2]) {
  float oth[16];
  #pragma unroll
  for (int i = 0; i < 16; ++i) oth[i] = __shfl_xor(X[i], 32);
  #pragma unroll
  for (int h = 0; h < 2; ++h) {
    float r8[8];
    #pragma unroll
    for (int j2 = 0; j2 < 8; ++j2) {
      float g0 = (j2 < 4) ? X[8 * h + j2] : oth[8 * h + j2 - 4];
      float g1 = (j2 < 4) ? oth[8 * h + 4 + j2] : X[8 * h + j2];
      r8[j2] = G ? g1 : g0;
    }
    union { short8 s8; unsigned int u[4]; } uh, ul;
    #pragma unroll
    for (int j = 0; j < 4; ++j) {
      unsigned int b0 = __float_as_uint(r8[2 * j]) & 0xFFFF0000u;
      unsigned int b1 = __float_as_uint(r8[2 * j + 1]) & 0xFFFF0000u;
      float l0 = r8[2 * j] - __uint_as_float(b0);
      float l1 = r8[2 * j + 1] - __uint_as_float(b1);
      uh.u[j] = (b0 >> 16) | b1;
      ul.u[j] = bf16r(l0) | (bf16r(l1) << 16);
    }
    bh[h] = uh.s8;
    bl[h] = ul.s8;
  }
}

__global__ __launch_bounds__(256) void expm_tchain_kernel(
    const __hip_bfloat16* __restrict__ flat,
    const float* __restrict__ q,
    const float* __restrict__ dtp,
    float* __restrict__ out_q,
    float* __restrict__ out_dlogp) {
  __shared__ __align__(16) unsigned int SL[4][16][33];
  const int tid = threadIdx.x;
  const int w = tid >> 6, lane = tid & 63;
  const int C = lane & 31, G = lane >> 5;
  const int m = blockIdx.x * 4 + w;
  const float dt = dtp[0];

  const uint4* fm = reinterpret_cast<const uint4*>(flat + (size_t)m * 1024);
  uint4 v0 = fm[lane];
  uint4 v1 = fm[lane + 64];
  {
    const int r0 = lane >> 2, kpb = (lane & 3) * 4;
    SL[w][kpb + 0][r0] = v0.x; SL[w][kpb + 1][r0] = v0.y;
    SL[w][kpb + 2][r0] = v0.z; SL[w][kpb + 3][r0] = v0.w;
    SL[w][kpb + 0][r0 + 16] = v1.x; SL[w][kpb + 1][r0 + 16] = v1.y;
    SL[w][kpb + 2][r0 + 16] = v1.z; SL[w][kpb + 3][r0 + 16] = v1.w;
  }

  union u4s8 { uint4 u4; short8 s8; unsigned int u[4]; };
  u4s8 t0, t1;
  {
    const char* base = reinterpret_cast<const char*>(flat) + (size_t)m * 2048 + C * 64 + G * 16;
    t0.u4 = *reinterpret_cast<const uint4*>(base);
    t1.u4 = *reinterpret_cast<const uint4*>(base + 32);
  }

  float sa = 0.f;
  {
    unsigned int a0[4] = {t0.u[0], t0.u[1], t0.u[2], t0.u[3]};
    unsigned int a1[4] = {t1.u[0], t1.u[1], t1.u[2], t1.u[3]};
    #pragma unroll
    for (int i = 0; i < 4; ++i) {
      sa += fabsf(__uint_as_float(a0[i] << 16)) + fabsf(__uint_as_float(a0[i] & 0xFFFF0000u));
      sa += fabsf(__uint_as_float(a1[i] << 16)) + fabsf(__uint_as_float(a1[i] & 0xFFFF0000u));
    }
  }
  sa += __shfl_xor(sa, 32);
  float nrm = sa;
  #pragma unroll
  for (int off = 1; off < 32; off <<= 1) nrm = fmaxf(nrm, __shfl_xor(nrm, off));

  int s = 0;
  float anrm = dt * nrm;
  if (anrm > 1.5f) {
    s = (int)ceilf(log2f(anrm * (1.0f / 1.5f)));
    s = s < 1 ? 1 : (s > 6 ? 6 : s);
  }
  const float u = dt * exp2f(-(float)s);

  unsigned int pt0[4], pt1[4];
  #pragma unroll
  for (int d = 0; d < 4; ++d) {
    pt0[d] = (unsigned int)__shfl_xor((int)t0.u[d], 32);
    pt1[d] = (unsigned int)__shfl_xor((int)t1.u[d], 32);
  }
  float E[16], dIa[16];
  float tr = 0.f;
  #pragma unroll
  for (int j = 0; j < 4; ++j) {
    #pragma unroll
    for (int e2 = 0; e2 < 4; ++e2) {
      const int i = 4 * j + e2;
      const int rd = e2 + 8 * j + 4 * G;
      const bool own = ((j & 1) == G);
      unsigned int dwO, dwP;
      if ((e2 >> 1) == 0) {
        dwO = G ? ((j < 2) ? t0.u[2] : t1.u[2]) : ((j < 2) ? t0.u[0] : t1.u[0]);
        dwP = G ? ((j < 2) ? pt0[2] : pt1[2]) : ((j < 2) ? pt0[0] : pt1[0]);
      } else {
        dwO = G ? ((j < 2) ? t0.u[3] : t1.u[3]) : ((j < 2) ? t0.u[1] : t1.u[1]);
        dwP = G ? ((j < 2) ? pt0[3] : pt1[3]) : ((j < 2) ? pt0[1] : pt1[1]);
      }
      unsigned int dw = own ? dwO : dwP;
      unsigned int h16 = (e2 & 1) ? (dw >> 16) : (dw & 0xFFFFu);
      float mv = __uint_as_float(h16 << 16);
      float dI = (rd == C) ? 1.0f : 0.0f;
      dIa[i] = dI;
      E[i] = dI + u * mv;
      tr += dI * mv;
    }
  }
  #pragma unroll
  for (int off = 1; off < 64; off <<= 1) tr += __shfl_xor(tr, off);
  if (lane == 0) out_dlogp[m] = dt * tr;

  WAITLDS;

  short8 Mfr[2];
  {
    const unsigned int selpat = (C & 1) ? 0x07060302u : 0x05040100u;
    #pragma unroll
    for (int h = 0; h < 2; ++h) {
      unsigned int rr[8];
      #pragma unroll
      for (int e = 0; e < 8; ++e) rr[e] = SL[w][C >> 1][16 * h + 8 * G + e];
      union { short8 s8; unsigned int u[4]; } mu;
      #pragma unroll
      for (int j = 0; j < 4; ++j)
        mu.u[j] = __builtin_amdgcn_perm(rr[2 * j + 1], rr[2 * j], selpat);
      Mfr[h] = mu.s8;
    }
  }

  float Qc[16];
  float ck = u * u * 0.5f;
  {
    f32x16 acc = {};
    acc = __builtin_amdgcn_mfma_f32_32x32x16_bf16(Mfr[0], t0.s8, acc, 0, 0, 0);
    acc = __builtin_amdgcn_mfma_f32_32x32x16_bf16(Mfr[1], t1.s8, acc, 0, 0, 0);
    #pragma unroll
    for (int i = 0; i < 16; ++i) { Qc[i] = acc[i]; E[i] += ck * Qc[i]; }
  }
  #pragma unroll
  for (int k = 3; k <= 8; ++k) {
    short8 bfr[2];
    d2b(Qc, G, bfr);
    f32x16 acc = {};
    acc = __builtin_amdgcn_mfma_f32_32x32x16_bf16(Mfr[0], bfr[0], acc, 0, 0, 0);
    acc = __builtin_amdgcn_mfma_f32_32x32x16_bf16(Mfr[1], bfr[1], acc, 0, 0, 0);
    ck *= u * (1.0f / (float)k);
    #pragma unroll
    for (int i = 0; i < 16; ++i) { Qc[i] = acc[i]; E[i] += ck * Qc[i]; }
  }

  short8 beh[2], bel[2];
  d2b_split(E, G, beh, bel);

  float qv = q[(size_t)m * 32 + C];
  const int nv = 1 << s;
  #pragma unroll 1
  for (int it = 0; it < nv; ++it) {
    unsigned int hb = __float_as_uint(qv) & 0xFFFF0000u;
    float lof = qv - __uint_as_float(hb);
    unsigned int pw = (hb >> 16) | (bf16r(lof) << 16);
    short8 vh[2], vl[2];
    #pragma unroll
    for (int h = 0; h < 2; ++h) {
      unsigned int g[8];
      #pragma unroll
      for (int e = 0; e < 8; ++e)
        g[e] = (unsigned int)__shfl((int)pw, 16 * h + 8 * G + e);
      union { short8 s8; unsigned int u[4]; } uh, ul;
      #pragma unroll
      for (int j = 0; j < 4; ++j) {
        uh.u[j] = __builtin_amdgcn_perm(g[2 * j + 1], g[2 * j], 0x05040100u);
        ul.u[j] = __builtin_amdgcn_perm(g[2 * j + 1], g[2 * j], 0x07060302u);
      }
      vh[h] = uh.s8;
      vl[h] = ul.s8;
    }
    f32x16 acc = {};
    acc = __builtin_amdgcn_mfma_f32_32x32x16_bf16(vh[0], beh[0], acc, 0, 0, 0);
    acc = __builtin_amdgcn_mfma_f32_32x32x16_bf16(vh[1], beh[1], acc, 0, 0, 0);
    acc = __builtin_amdgcn_mfma_f32_32x32x16_bf16(vl[0], beh[0], acc, 0, 0, 0);
    acc = __builtin_amdgcn_mfma_f32_32x32x16_bf16(vl[1], beh[1], acc, 0, 0, 0);
    acc = __builtin_amdgcn_mfma_f32_32x32x16_bf16(vh[0], bel[0], acc, 0, 0, 0);
    acc = __builtin_amdgcn_mfma_f32_32x32x16_bf16(vh[1], bel[1], acc, 0, 0, 0);
    qv = acc[0];
  }
  if (G == 0) out_q[(size_t)m * 32 + C] = qv;
}

extern "C" void kernel_launch(void* const* d_in, const int* in_sizes, int n_in,
                              void* d_out, int out_size, void* d_ws, size_t ws_size,
                              hipStream_t stream) {
  const float* q    = (const float*)d_in[0];
  const float* p    = (const float*)d_in[1];
  const float* t    = (const float*)d_in[2];
  const float* dt   = (const float*)d_in[3];
  const float* W0   = (const float*)d_in[4];
  const float* b0   = (const float*)d_in[5];
  const float* W1   = (const float*)d_in[6];
  const float* b1   = (const float*)d_in[7];
  const float* W2   = (const float*)d_in[8];
  const float* b2   = (const float*)d_in[9];
  const float* W3   = (const float*)d_in[10];
  const float* b3   = (const float*)d_in[11];
  const float* Wout = (const float*)d_in[12];
  const float* bout = (const float*)d_in[13];

  // ws layout (all bf16 activations)
  __hip_bfloat16* flatb = (__hip_bfloat16*)d_ws;                 // B*1024
  __hip_bfloat16* act1  = flatb + (size_t)BTOT * 1024;           // B*512
  __hip_bfloat16* act2  = act1 + (size_t)BTOT * 512;             // B*512
  __hip_bfloat16* pbf   = act2 + (size_t)BTOT * 512;             // B*32
  __hip_bfloat16* Wt0   = pbf + (size_t)BTOT * 32;
  __hip_bfloat16* Wt1   = Wt0 + 512 * 32;
  __hip_bfloat16* Wt2   = Wt1 + 512 * 512;
  __hip_bfloat16* Wt3   = Wt2 + 512 * 512;
  __hip_bfloat16* WtO   = Wt3 + 512 * 512;

  dim3 blk(256);
  convert_p_kernel<<<BTOT * 32 / 1024, blk, 0, stream>>>(p, pbf);
  transpose_w_kernel<<<dim3(1, 16),  blk, 0, stream>>>(W0,   Wt0, 32,  512);
  transpose_w_kernel<<<dim3(16, 16), blk, 0, stream>>>(W1,   Wt1, 512, 512);
  transpose_w_kernel<<<dim3(16, 16), blk, 0, stream>>>(W2,   Wt2, 512, 512);
  transpose_w_kernel<<<dim3(16, 16), blk, 0, stream>>>(W3,   Wt3, 512, 512);
  transpose_w_kernel<<<dim3(16, 32), blk, 0, stream>>>(Wout, WtO, 512, 1024);

  // grid = (bn, bm): bn fastest -> X row-panel reused by adjacent dispatches
  mlp_mfma_kernel<32, 0><<<dim3(4, 128), blk, 0, stream>>>(
      pbf, 32, 32, t, Wt0, W0 + 32 * 512, b0, act1, 512);
  mlp_mfma_kernel<64, 0><<<dim3(4, 128), blk, 0, stream>>>(
      act1, 512, 512, t, Wt1, W1 + 512 * 512, b1, act2, 512);
  mlp_mfma_kernel<64, 0><<<dim3(4, 128), blk, 0, stream>>>(
      act2, 512, 512, t, Wt2, W2 + 512 * 512, b2, act1, 512);
  mlp_mfma_kernel<64, 0><<<dim3(4, 128), blk, 0, stream>>>(
      act1, 512, 512, t, Wt3, W3 + 512 * 512, b3, act2, 512);
  mlp_mfma_kernel<64, 1><<<dim3(8, 128), blk, 0, stream>>>(
      act2, 512, 512, t, WtO, Wout + 512 * 1024, bout, flatb, 1024);

  float* out_q     = (float*)d_out;
  float* out_dlogp = out_q + (size_t)BTOT * 32;
  expm_tchain_kernel<<<BTOT / 4, blk, 0, stream>>>(flatb, q, dt, out_q, out_dlogp);
}

// Round 11
// 151.199 us; speedup vs baseline: 1.1981x; 1.0797x over previous
//
#include <hip/hip_runtime.h>
#include <hip/hip_bf16.h>
#include <math.h>

#define BTOT 16384

typedef __attribute__((ext_vector_type(8))) short short8;
typedef __attribute__((ext_vector_type(4))) float f32x4;
typedef __attribute__((ext_vector_type(16))) float f32x16;

__device__ __forceinline__ float selu_f(float x) {
  const float scale = 1.0507009873554805f;
  const float alpha = 1.6732632423543772f;
  return scale * (x > 0.0f ? x : alpha * expm1f(x));
}

// ---------------- prep: p -> bf16 ----------------
__global__ __launch_bounds__(256) void convert_p_kernel(
    const float* __restrict__ p, __hip_bfloat16* __restrict__ out) {
  int i = (blockIdx.x * 256 + threadIdx.x) * 4;
  float4 v = *reinterpret_cast<const float4*>(p + i);
  out[i + 0] = __float2bfloat16(v.x);
  out[i + 1] = __float2bfloat16(v.y);
  out[i + 2] = __float2bfloat16(v.z);
  out[i + 3] = __float2bfloat16(v.w);
}

// ---------------- prep: W[K][N] f32 -> Wt[N][K] bf16 (t-row excluded) ---------
__global__ __launch_bounds__(256) void transpose_w_kernel(
    const float* __restrict__ W, __hip_bfloat16* __restrict__ Wt, int K, int N) {
  __shared__ float tile[32][33];
  const int kb = blockIdx.x * 32, nb = blockIdx.y * 32;
  const int tx = threadIdx.x & 31, ty = threadIdx.x >> 5;
  #pragma unroll
  for (int rr = 0; rr < 4; ++rr) {
    int kl = ty + rr * 8;
    tile[kl][tx] = W[(size_t)(kb + kl) * N + nb + tx];
  }
  __syncthreads();
  #pragma unroll
  for (int rr = 0; rr < 4; ++rr) {
    int nl = ty + rr * 8;
    Wt[(size_t)(nb + nl) * K + kb + tx] = __float2bfloat16(tile[tx][nl]);
  }
}

// ---------------- MFMA MLP layer, 128x128 tile (r8 config: bm fastest) -------
// MODE 0: selu + bf16 store.  MODE 1: clip(+-20) + bf16 store (final layer).
// NOTE (r9/r10 lessons): BK=64 + 128x128 + bm-fastest grid is a 3x-defended
// local optimum. Wide-N (1 blk/CU) and bn-fastest grid both regressed.
template<int BK, int MODE>
__global__ __launch_bounds__(256) void mlp_mfma_kernel(
    const __hip_bfloat16* __restrict__ X, int ldx, int Kc,
    const float* __restrict__ tvec,
    const __hip_bfloat16* __restrict__ Wt,
    const float* __restrict__ Wlast,
    const float* __restrict__ bias,
    __hip_bfloat16* __restrict__ Yout, int ldy) {
  constexpr int NBLK = BK / 8;
  constexpr int AB = 128 * BK * 2;
  constexpr int IPW = AB / 1024 / 4;
  __shared__ char lds[4 * AB];
  const int tid = threadIdx.x;
  const int w = tid >> 6, lane = tid & 63;
  const int wr = w >> 1, wc = w & 1;
  const int rowbase = blockIdx.x * 128, colbase = blockIdx.y * 128;

  const __hip_bfloat16* srcA[IPW];
  const __hip_bfloat16* srcB[IPW];
  int ldsoff[IPW];
  #pragma unroll
  for (int i = 0; i < IPW; ++i) {
    int f = (w * IPW + i) * 64 + lane;
    int r = f / NBLK, slot = f % NBLK;
    int kb = slot ^ (r & (NBLK - 1));
    srcA[i] = X + (size_t)(rowbase + r) * ldx + kb * 8;
    srcB[i] = Wt + (size_t)(colbase + r) * Kc + kb * 8;
    ldsoff[i] = (w * IPW + i) * 1024;
  }

  f32x4 acc[4][4] = {};

  int aoff[4], amask[4], boff[4], bmask[4];
  #pragma unroll
  for (int i = 0; i < 4; ++i) {
    int ra = wr * 64 + i * 16 + (lane & 15);
    aoff[i] = ra * BK * 2;
    amask[i] = ra & (NBLK - 1);
    int cb = wc * 64 + i * 16 + (lane & 15);
    boff[i] = cb * BK * 2;
    bmask[i] = cb & (NBLK - 1);
  }
  const int kgrp = lane >> 4;

  auto stage_tile = [&](int buf, int t) {
    char* ab = lds + buf * 2 * AB;
    #pragma unroll
    for (int i = 0; i < IPW; ++i) {
      __builtin_amdgcn_global_load_lds(
          (const __attribute__((address_space(1))) void*)(srcA[i] + t * BK),
          (__attribute__((address_space(3))) void*)(ab + ldsoff[i]), 16, 0, 0);
      __builtin_amdgcn_global_load_lds(
          (const __attribute__((address_space(1))) void*)(srcB[i] + t * BK),
          (__attribute__((address_space(3))) void*)(ab + AB + ldsoff[i]), 16, 0, 0);
    }
  };

  auto compute_tile = [&](int buf) {
    const char* Abse = lds + buf * 2 * AB;
    const char* Bbse = Abse + AB;
    #pragma unroll
    for (int kh = 0; kh < BK / 32; ++kh) {
      short8 a[4], b[4];
      const int kb = kh * 4 + kgrp;
      #pragma unroll
      for (int i = 0; i < 4; ++i) {
        a[i] = *reinterpret_cast<const short8*>(Abse + aoff[i] + ((kb ^ amask[i]) * 16));
        b[i] = *reinterpret_cast<const short8*>(Bbse + boff[i] + ((kb ^ bmask[i]) * 16));
      }
      #pragma unroll
      for (int i = 0; i < 4; ++i)
        #pragma unroll
        for (int j = 0; j < 4; ++j)
          acc[i][j] = __builtin_amdgcn_mfma_f32_16x16x32_bf16(a[i], b[j], acc[i][j], 0, 0, 0);
    }
  };

  const int nt = Kc / BK;
  stage_tile(0, 0);
  asm volatile("s_waitcnt vmcnt(0)" ::: "memory");
  __syncthreads();
  int buf = 0;
  #pragma unroll 1
  for (int t = 0; t < nt - 1; ++t) {
    stage_tile(buf ^ 1, t + 1);
    compute_tile(buf);
    asm volatile("s_waitcnt vmcnt(0)" ::: "memory");
    __syncthreads();
    buf ^= 1;
  }
  compute_tile(buf);

  const int colloc = lane & 15;
  const int rowgrp = lane >> 4;
  float wl[4], bb[4];
  #pragma unroll
  for (int j = 0; j < 4; ++j) {
    int col = colbase + wc * 64 + j * 16 + colloc;
    wl[j] = Wlast[col];
    bb[j] = bias[col];
  }
  #pragma unroll
  for (int i = 0; i < 4; ++i) {
    #pragma unroll
    for (int e = 0; e < 4; ++e) {
      int row = rowbase + wr * 64 + i * 16 + rowgrp * 4 + e;
      float tv = tvec[row];
      #pragma unroll
      for (int j = 0; j < 4; ++j) {
        float v = acc[i][j][e] + tv * wl[j] + bb[j];
        if (MODE == 0) v = selu_f(v);
        else           v = fminf(fmaxf(v, -20.f), 20.f);
        int col = colbase + wc * 64 + j * 16 + colloc;
        Yout[(size_t)row * ldy + col] = __float2bfloat16(v);
      }
    }
  }
}

// ---------------- expm: transposed chain, 2 matrices/wave ILP ----------------
// Same verified structure as r8 (M = A^T chain, E^T state in D-layout, MFMA
// matvec squaring), with: (a) TWO independent matrices per wave so the two
// serial chains interleave (latency was 3x the issue floor), (b) lean d2b
// (8 shfl instead of 16: pre-select the only-used half before shuffling),
// (c) Taylor order 6 (theta=1.0): 5 chain products, err ~5e-4.
#define WAITLDS asm volatile("s_waitcnt lgkmcnt(0)" ::: "memory")

__device__ __forceinline__ unsigned int bf16r(float x) {
  return (__float_as_uint(x) + 0x8000u) >> 16;
}

// Lean d2b: G=0 lanes need partner X[{0..3,8..11}]; G=1 need partner
// X[{4..7,12..15}] -> pre-select send value, 8 shfls total.
__device__ __forceinline__ void d2b_lean(const float (&X)[16], int G, short8 (&bfr)[2]) {
  float rcv[8];
  #pragma unroll
  for (int j = 0; j < 8; ++j) {
    const int hp = j >> 2, tt = j & 3;
    float snd = G ? X[8 * hp + tt] : X[8 * hp + 4 + tt];
    rcv[j] = __shfl_xor(snd, 32);
  }
  #pragma unroll
  for (int h = 0; h < 2; ++h) {
    float r8v[8];
    #pragma unroll
    for (int j2 = 0; j2 < 8; ++j2) {
      if (j2 < 4) r8v[j2] = G ? rcv[4 * h + j2] : X[8 * h + j2];
      else        r8v[j2] = G ? X[8 * h + j2] : rcv[4 * h + j2 - 4];
    }
    union { short8 s8; unsigned int u[4]; } bu;
    #pragma unroll
    for (int j = 0; j < 4; ++j)
      bu.u[j] = bf16r(r8v[2 * j]) | (bf16r(r8v[2 * j + 1]) << 16);
    bfr[h] = bu.s8;
  }
}

__device__ __forceinline__ void d2b_split_lean(const float (&X)[16], int G,
                                               short8 (&bh)[2], short8 (&bl)[2]) {
  float rcv[8];
  #pragma unroll
  for (int j = 0; j < 8; ++j) {
    const int hp = j >> 2, tt = j & 3;
    float snd = G ? X[8 * hp + tt] : X[8 * hp + 4 + tt];
    rcv[j] = __shfl_xor(snd, 32);
  }
  #pragma unroll
  for (int h = 0; h < 2; ++h) {
    float r8v[8];
    #pragma unroll
    for (int j2 = 0; j2 < 8; ++j2) {
      if (j2 < 4) r8v[j2] = G ? rcv[4 * h + j2] : X[8 * h + j2];
      else        r8v[j2] = G ? X[8 * h + j2] : rcv[4 * h + j2 - 4];
    }
    union { short8 s8; unsigned int u[4]; } uh, ul;
    #pragma unroll
    for (int j = 0; j < 4; ++j) {
      unsigned int b0 = __float_as_uint(r8v[2 * j]) & 0xFFFF0000u;
      unsigned int b1 = __float_as_uint(r8v[2 * j + 1]) & 0xFFFF0000u;
      float l0 = r8v[2 * j] - __uint_as_float(b0);
      float l1 = r8v[2 * j + 1] - __uint_as_float(b1);
      uh.u[j] = (b0 >> 16) | b1;
      ul.u[j] = bf16r(l0) | (bf16r(l1) << 16);
    }
    bh[h] = uh.s8;
    bl[h] = ul.s8;
  }
}

union u4s8 { uint4 u4; short8 s8; unsigned int u[4]; };

__global__ __launch_bounds__(256) void expm_ilp2_kernel(
    const __hip_bfloat16* __restrict__ flat,
    const float* __restrict__ q,
    const float* __restrict__ dtp,
    float* __restrict__ out_q,
    float* __restrict__ out_dlogp) {
  __shared__ __align__(16) unsigned int SL[4][2][16][33];
  const int tid = threadIdx.x;
  const int w = tid >> 6, lane = tid & 63;
  const int C = lane & 31, G = lane >> 5;
  const int m0 = blockIdx.x * 8 + w * 2;
  const float dt = dtp[0];

  u4s8 t0[2], t1[2];
  float E[2][16];
  float uu[2];
  int nv[2];

  // ---- per-matrix: load, stage transpose slab, norm, E-init, trace ----
  #pragma unroll
  for (int mm = 0; mm < 2; ++mm) {
    const int m = m0 + mm;
    const uint4* fm = reinterpret_cast<const uint4*>(flat + (size_t)m * 1024);
    uint4 v0 = fm[lane];
    uint4 v1 = fm[lane + 64];
    {
      const int r0 = lane >> 2, kpb = (lane & 3) * 4;
      SL[w][mm][kpb + 0][r0] = v0.x; SL[w][mm][kpb + 1][r0] = v0.y;
      SL[w][mm][kpb + 2][r0] = v0.z; SL[w][mm][kpb + 3][r0] = v0.w;
      SL[w][mm][kpb + 0][r0 + 16] = v1.x; SL[w][mm][kpb + 1][r0 + 16] = v1.y;
      SL[w][mm][kpb + 2][r0 + 16] = v1.z; SL[w][mm][kpb + 3][r0 + 16] = v1.w;
    }
    {
      const char* base = reinterpret_cast<const char*>(flat) + (size_t)m * 2048 + C * 64 + G * 16;
      t0[mm].u4 = *reinterpret_cast<const uint4*>(base);
      t1[mm].u4 = *reinterpret_cast<const uint4*>(base + 32);
    }

    // inf-norm (row C abs-sum over both halves)
    float sa = 0.f;
    #pragma unroll
    for (int i = 0; i < 4; ++i) {
      sa += fabsf(__uint_as_float(t0[mm].u[i] << 16)) + fabsf(__uint_as_float(t0[mm].u[i] & 0xFFFF0000u));
      sa += fabsf(__uint_as_float(t1[mm].u[i] << 16)) + fabsf(__uint_as_float(t1[mm].u[i] & 0xFFFF0000u));
    }
    sa += __shfl_xor(sa, 32);
    float nrm = sa;
    #pragma unroll
    for (int off = 1; off < 32; off <<= 1) nrm = fmaxf(nrm, __shfl_xor(nrm, off));

    int s = 0;
    float anrm = dt * nrm;
    if (anrm > 1.0f) {
      s = (int)ceilf(log2f(anrm));
      s = s < 1 ? 1 : (s > 6 ? 6 : s);
    }
    nv[mm] = 1 << s;
    const float u = dt * exp2f(-(float)s);
    uu[mm] = u;

    // E = I + u*M (M = A^T) in D-layout; trace on the fly
    unsigned int pt0[4], pt1[4];
    #pragma unroll
    for (int d = 0; d < 4; ++d) {
      pt0[d] = (unsigned int)__shfl_xor((int)t0[mm].u[d], 32);
      pt1[d] = (unsigned int)__shfl_xor((int)t1[mm].u[d], 32);
    }
    float tr = 0.f;
    #pragma unroll
    for (int j = 0; j < 4; ++j) {
      #pragma unroll
      for (int e2 = 0; e2 < 4; ++e2) {
        const int i = 4 * j + e2;
        const int rd = e2 + 8 * j + 4 * G;
        const bool own = ((j & 1) == G);
        unsigned int dwO, dwP;
        if ((e2 >> 1) == 0) {
          dwO = G ? ((j < 2) ? t0[mm].u[2] : t1[mm].u[2]) : ((j < 2) ? t0[mm].u[0] : t1[mm].u[0]);
          dwP = G ? ((j < 2) ? pt0[2] : pt1[2]) : ((j < 2) ? pt0[0] : pt1[0]);
        } else {
          dwO = G ? ((j < 2) ? t0[mm].u[3] : t1[mm].u[3]) : ((j < 2) ? t0[mm].u[1] : t1[mm].u[1]);
          dwP = G ? ((j < 2) ? pt0[3] : pt1[3]) : ((j < 2) ? pt0[1] : pt1[1]);
        }
        unsigned int dw = own ? dwO : dwP;
        unsigned int h16 = (e2 & 1) ? (dw >> 16) : (dw & 0xFFFFu);
        float mv = __uint_as_float(h16 << 16);
        float dI = (rd == C) ? 1.0f : 0.0f;
        E[mm][i] = dI + u * mv;
        tr += dI * mv;
      }
    }
    #pragma unroll
    for (int off = 1; off < 64; off <<= 1) tr += __shfl_xor(tr, off);
    if (lane == 0) out_dlogp[m] = dt * tr;
  }

  WAITLDS;

  // M A-operand frags per matrix
  short8 Mfr[2][2];
  {
    const unsigned int selpat = (C & 1) ? 0x07060302u : 0x05040100u;
    #pragma unroll
    for (int mm = 0; mm < 2; ++mm) {
      #pragma unroll
      for (int h = 0; h < 2; ++h) {
        unsigned int rr[8];
        #pragma unroll
        for (int e = 0; e < 8; ++e) rr[e] = SL[w][mm][C >> 1][16 * h + 8 * G + e];
        union { short8 s8; unsigned int u[4]; } mu;
        #pragma unroll
        for (int j = 0; j < 4; ++j)
          mu.u[j] = __builtin_amdgcn_perm(rr[2 * j + 1], rr[2 * j], selpat);
        Mfr[mm][h] = mu.s8;
      }
    }
  }

  // chain: order-6 Taylor, 5 products; two independent chains interleaved
  float Qc[2][16];
  float ck[2];
  #pragma unroll
  for (int mm = 0; mm < 2; ++mm) {
    ck[mm] = uu[mm] * uu[mm] * 0.5f;
    f32x16 acc = {};
    acc = __builtin_amdgcn_mfma_f32_32x32x16_bf16(Mfr[mm][0], t0[mm].s8, acc, 0, 0, 0);
    acc = __builtin_amdgcn_mfma_f32_32x32x16_bf16(Mfr[mm][1], t1[mm].s8, acc, 0, 0, 0);
    #pragma unroll
    for (int i = 0; i < 16; ++i) { Qc[mm][i] = acc[i]; E[mm][i] += ck[mm] * acc[i]; }
  }
  #pragma unroll
  for (int k = 3; k <= 6; ++k) {
    #pragma unroll
    for (int mm = 0; mm < 2; ++mm) {
      short8 bfr[2];
      d2b_lean(Qc[mm], G, bfr);
      f32x16 acc = {};
      acc = __builtin_amdgcn_mfma_f32_32x32x16_bf16(Mfr[mm][0], bfr[0], acc, 0, 0, 0);
      acc = __builtin_amdgcn_mfma_f32_32x32x16_bf16(Mfr[mm][1], bfr[1], acc, 0, 0, 0);
      ck[mm] *= uu[mm] * (1.0f / (float)k);
      #pragma unroll
      for (int i = 0; i < 16; ++i) { Qc[mm][i] = acc[i]; E[mm][i] += ck[mm] * acc[i]; }
    }
  }

  // E -> split B-op frags; matvec loop (shared trip count, per-matrix select)
  short8 beh[2][2], bel[2][2];
  #pragma unroll
  for (int mm = 0; mm < 2; ++mm)
    d2b_split_lean(E[mm], G, beh[mm], bel[mm]);

  float qv[2];
  qv[0] = q[(size_t)m0 * 32 + C];
  qv[1] = q[(size_t)(m0 + 1) * 32 + C];
  const int nvmax = nv[0] > nv[1] ? nv[0] : nv[1];
  #pragma unroll 1
  for (int it = 0; it < nvmax; ++it) {
    #pragma unroll
    for (int mm = 0; mm < 2; ++mm) {
      unsigned int hb = __float_as_uint(qv[mm]) & 0xFFFF0000u;
      float lof = qv[mm] - __uint_as_float(hb);
      unsigned int pw = (hb >> 16) | (bf16r(lof) << 16);
      short8 vh[2], vl[2];
      #pragma unroll
      for (int h = 0; h < 2; ++h) {
        unsigned int g[8];
        #pragma unroll
        for (int e = 0; e < 8; ++e)
          g[e] = (unsigned int)__shfl((int)pw, 16 * h + 8 * G + e);
        union { short8 s8; unsigned int u[4]; } uh, ul;
        #pragma unroll
        for (int j = 0; j < 4; ++j) {
          uh.u[j] = __builtin_amdgcn_perm(g[2 * j + 1], g[2 * j], 0x05040100u);
          ul.u[j] = __builtin_amdgcn_perm(g[2 * j + 1], g[2 * j], 0x07060302u);
        }
        vh[h] = uh.s8;
        vl[h] = ul.s8;
      }
      f32x16 acc = {};
      acc = __builtin_amdgcn_mfma_f32_32x32x16_bf16(vh[0], beh[mm][0], acc, 0, 0, 0);
      acc = __builtin_amdgcn_mfma_f32_32x32x16_bf16(vh[1], beh[mm][1], acc, 0, 0, 0);
      acc = __builtin_amdgcn_mfma_f32_32x32x16_bf16(vl[0], beh[mm][0], acc, 0, 0, 0);
      acc = __builtin_amdgcn_mfma_f32_32x32x16_bf16(vl[1], beh[mm][1], acc, 0, 0, 0);
      acc = __builtin_amdgcn_mfma_f32_32x32x16_bf16(vh[0], bel[mm][0], acc, 0, 0, 0);
      acc = __builtin_amdgcn_mfma_f32_32x32x16_bf16(vh[1], bel[mm][1], acc, 0, 0, 0);
      qv[mm] = (it < nv[mm]) ? acc[0] : qv[mm];
    }
  }
  if (G == 0) {
    out_q[(size_t)m0 * 32 + C] = qv[0];
    out_q[(size_t)(m0 + 1) * 32 + C] = qv[1];
  }
}

extern "C" void kernel_launch(void* const* d_in, const int* in_sizes, int n_in,
                              void* d_out, int out_size, void* d_ws, size_t ws_size,
                              hipStream_t stream) {
  const float* q    = (const float*)d_in[0];
  const float* p    = (const float*)d_in[1];
  const float* t    = (const float*)d_in[2];
  const float* dt   = (const float*)d_in[3];
  const float* W0   = (const float*)d_in[4];
  const float* b0   = (const float*)d_in[5];
  const float* W1   = (const float*)d_in[6];
  const float* b1   = (const float*)d_in[7];
  const float* W2   = (const float*)d_in[8];
  const float* b2   = (const float*)d_in[9];
  const float* W3   = (const float*)d_in[10];
  const float* b3   = (const float*)d_in[11];
  const float* Wout = (const float*)d_in[12];
  const float* bout = (const float*)d_in[13];

  // ws layout (all bf16 activations)
  __hip_bfloat16* flatb = (__hip_bfloat16*)d_ws;                 // B*1024
  __hip_bfloat16* act1  = flatb + (size_t)BTOT * 1024;           // B*512
  __hip_bfloat16* act2  = act1 + (size_t)BTOT * 512;             // B*512
  __hip_bfloat16* pbf   = act2 + (size_t)BTOT * 512;             // B*32
  __hip_bfloat16* Wt0   = pbf + (size_t)BTOT * 32;
  __hip_bfloat16* Wt1   = Wt0 + 512 * 32;
  __hip_bfloat16* Wt2   = Wt1 + 512 * 512;
  __hip_bfloat16* Wt3   = Wt2 + 512 * 512;
  __hip_bfloat16* WtO   = Wt3 + 512 * 512;

  dim3 blk(256);
  convert_p_kernel<<<BTOT * 32 / 1024, blk, 0, stream>>>(p, pbf);
  transpose_w_kernel<<<dim3(1, 16),  blk, 0, stream>>>(W0,   Wt0, 32,  512);
  transpose_w_kernel<<<dim3(16, 16), blk, 0, stream>>>(W1,   Wt1, 512, 512);
  transpose_w_kernel<<<dim3(16, 16), blk, 0, stream>>>(W2,   Wt2, 512, 512);
  transpose_w_kernel<<<dim3(16, 16), blk, 0, stream>>>(W3,   Wt3, 512, 512);
  transpose_w_kernel<<<dim3(16, 32), blk, 0, stream>>>(Wout, WtO, 512, 1024);

  // r8 grids (bm fastest)
  mlp_mfma_kernel<32, 0><<<dim3(128, 4), blk, 0, stream>>>(
      pbf, 32, 32, t, Wt0, W0 + 32 * 512, b0, act1, 512);
  mlp_mfma_kernel<64, 0><<<dim3(128, 4), blk, 0, stream>>>(
      act1, 512, 512, t, Wt1, W1 + 512 * 512, b1, act2, 512);
  mlp_mfma_kernel<64, 0><<<dim3(128, 4), blk, 0, stream>>>(
      act2, 512, 512, t, Wt2, W2 + 512 * 512, b2, act1, 512);
  mlp_mfma_kernel<64, 0><<<dim3(128, 4), blk, 0, stream>>>(
      act1, 512, 512, t, Wt3, W3 + 512 * 512, b3, act2, 512);
  mlp_mfma_kernel<64, 1><<<dim3(128, 8), blk, 0, stream>>>(
      act2, 512, 512, t, WtO, Wout + 512 * 1024, bout, flatb, 1024);

  float* out_q     = (float*)d_out;
  float* out_dlogp = out_q + (size_t)BTOT * 32;
  expm_ilp2_kernel<<<BTOT / 8, blk, 0, stream>>>(flatb, q, dt, out_q, out_dlogp);
}

// Round 12
// 141.328 us; speedup vs baseline: 1.2818x; 1.0698x over previous
//
#include <hip/hip_runtime.h>
#include <hip/hip_bf16.h>
#include <math.h>

#define BTOT 16384

typedef __attribute__((ext_vector_type(8))) short short8;
typedef __attribute__((ext_vector_type(4))) float f32x4;
typedef __attribute__((ext_vector_type(16))) float f32x16;

__device__ __forceinline__ float selu_f(float x) {
  const float scale = 1.0507009873554805f;
  const float alpha = 1.6732632423543772f;
  return scale * (x > 0.0f ? x : alpha * expm1f(x));
}

// ---------------- fused prep: p->bf16 + all 5 weight transposes --------------
// One launch instead of six serial ones (each was launch/tail-bound).
// Block map: [0,512) convert_p; then transpose tiles:
//   [512,528)  W0  (1x16,  K=32,  N=512)
//   [528,784)  W1  (16x16, K=512, N=512)
//   [784,1040) W2
//   [1040,1296) W3
//   [1296,1808) Wout (16x32, K=512, N=1024)
__global__ __launch_bounds__(256) void prep_kernel(
    const float* __restrict__ p, __hip_bfloat16* __restrict__ pbf,
    const float* __restrict__ W0, __hip_bfloat16* __restrict__ Wt0,
    const float* __restrict__ W1, __hip_bfloat16* __restrict__ Wt1,
    const float* __restrict__ W2, __hip_bfloat16* __restrict__ Wt2,
    const float* __restrict__ W3, __hip_bfloat16* __restrict__ Wt3,
    const float* __restrict__ Wout, __hip_bfloat16* __restrict__ WtO) {
  __shared__ float tile[32][33];
  const int bid = blockIdx.x;
  if (bid < 512) {
    int i = (bid * 256 + threadIdx.x) * 4;
    float4 v = *reinterpret_cast<const float4*>(p + i);
    pbf[i + 0] = __float2bfloat16(v.x);
    pbf[i + 1] = __float2bfloat16(v.y);
    pbf[i + 2] = __float2bfloat16(v.z);
    pbf[i + 3] = __float2bfloat16(v.w);
    return;
  }
  const int t = bid - 512;
  const float* W;
  __hip_bfloat16* Wt;
  int K, N, kb, nb;
  if (t < 16)        { W = W0;   Wt = Wt0; K = 32;  N = 512;  kb = 0;  nb = t; }
  else if (t < 272)  { int u = t - 16;   W = W1;   Wt = Wt1; K = 512; N = 512;  kb = u & 15; nb = u >> 4; }
  else if (t < 528)  { int u = t - 272;  W = W2;   Wt = Wt2; K = 512; N = 512;  kb = u & 15; nb = u >> 4; }
  else if (t < 784)  { int u = t - 528;  W = W3;   Wt = Wt3; K = 512; N = 512;  kb = u & 15; nb = u >> 4; }
  else               { int u = t - 784;  W = Wout; Wt = WtO; K = 512; N = 1024; kb = u & 15; nb = u >> 4; }
  kb *= 32; nb *= 32;
  const int tx = threadIdx.x & 31, ty = threadIdx.x >> 5;
  #pragma unroll
  for (int rr = 0; rr < 4; ++rr) {
    int kl = ty + rr * 8;
    tile[kl][tx] = W[(size_t)(kb + kl) * N + nb + tx];
  }
  __syncthreads();
  #pragma unroll
  for (int rr = 0; rr < 4; ++rr) {
    int nl = ty + rr * 8;
    Wt[(size_t)(nb + nl) * K + kb + tx] = __float2bfloat16(tile[tx][nl]);
  }
}

// ---------------- MFMA MLP layer, 128x128 tile (r8 config: bm fastest) -------
// MODE 0: selu + bf16 store.  MODE 1: clip(+-20) + bf16 store (final layer).
// NOTE (r9/r10 lessons): BK=64 + 128x128 + bm-fastest grid is a 3x-defended
// local optimum. Wide-N (1 blk/CU) and bn-fastest grid both regressed.
template<int BK, int MODE>
__global__ __launch_bounds__(256) void mlp_mfma_kernel(
    const __hip_bfloat16* __restrict__ X, int ldx, int Kc,
    const float* __restrict__ tvec,
    const __hip_bfloat16* __restrict__ Wt,
    const float* __restrict__ Wlast,
    const float* __restrict__ bias,
    __hip_bfloat16* __restrict__ Yout, int ldy) {
  constexpr int NBLK = BK / 8;
  constexpr int AB = 128 * BK * 2;
  constexpr int IPW = AB / 1024 / 4;
  __shared__ char lds[4 * AB];
  const int tid = threadIdx.x;
  const int w = tid >> 6, lane = tid & 63;
  const int wr = w >> 1, wc = w & 1;
  const int rowbase = blockIdx.x * 128, colbase = blockIdx.y * 128;

  const __hip_bfloat16* srcA[IPW];
  const __hip_bfloat16* srcB[IPW];
  int ldsoff[IPW];
  #pragma unroll
  for (int i = 0; i < IPW; ++i) {
    int f = (w * IPW + i) * 64 + lane;
    int r = f / NBLK, slot = f % NBLK;
    int kb = slot ^ (r & (NBLK - 1));
    srcA[i] = X + (size_t)(rowbase + r) * ldx + kb * 8;
    srcB[i] = Wt + (size_t)(colbase + r) * Kc + kb * 8;
    ldsoff[i] = (w * IPW + i) * 1024;
  }

  f32x4 acc[4][4] = {};

  int aoff[4], amask[4], boff[4], bmask[4];
  #pragma unroll
  for (int i = 0; i < 4; ++i) {
    int ra = wr * 64 + i * 16 + (lane & 15);
    aoff[i] = ra * BK * 2;
    amask[i] = ra & (NBLK - 1);
    int cb = wc * 64 + i * 16 + (lane & 15);
    boff[i] = cb * BK * 2;
    bmask[i] = cb & (NBLK - 1);
  }
  const int kgrp = lane >> 4;

  auto stage_tile = [&](int buf, int t) {
    char* ab = lds + buf * 2 * AB;
    #pragma unroll
    for (int i = 0; i < IPW; ++i) {
      __builtin_amdgcn_global_load_lds(
          (const __attribute__((address_space(1))) void*)(srcA[i] + t * BK),
          (__attribute__((address_space(3))) void*)(ab + ldsoff[i]), 16, 0, 0);
      __builtin_amdgcn_global_load_lds(
          (const __attribute__((address_space(1))) void*)(srcB[i] + t * BK),
          (__attribute__((address_space(3))) void*)(ab + AB + ldsoff[i]), 16, 0, 0);
    }
  };

  auto compute_tile = [&](int buf) {
    const char* Abse = lds + buf * 2 * AB;
    const char* Bbse = Abse + AB;
    #pragma unroll
    for (int kh = 0; kh < BK / 32; ++kh) {
      short8 a[4], b[4];
      const int kb = kh * 4 + kgrp;
      #pragma unroll
      for (int i = 0; i < 4; ++i) {
        a[i] = *reinterpret_cast<const short8*>(Abse + aoff[i] + ((kb ^ amask[i]) * 16));
        b[i] = *reinterpret_cast<const short8*>(Bbse + boff[i] + ((kb ^ bmask[i]) * 16));
      }
      #pragma unroll
      for (int i = 0; i < 4; ++i)
        #pragma unroll
        for (int j = 0; j < 4; ++j)
          acc[i][j] = __builtin_amdgcn_mfma_f32_16x16x32_bf16(a[i], b[j], acc[i][j], 0, 0, 0);
    }
  };

  const int nt = Kc / BK;
  stage_tile(0, 0);
  asm volatile("s_waitcnt vmcnt(0)" ::: "memory");
  __syncthreads();
  int buf = 0;
  #pragma unroll 1
  for (int t = 0; t < nt - 1; ++t) {
    stage_tile(buf ^ 1, t + 1);
    compute_tile(buf);
    asm volatile("s_waitcnt vmcnt(0)" ::: "memory");
    __syncthreads();
    buf ^= 1;
  }
  compute_tile(buf);

  const int colloc = lane & 15;
  const int rowgrp = lane >> 4;
  float wl[4], bb[4];
  #pragma unroll
  for (int j = 0; j < 4; ++j) {
    int col = colbase + wc * 64 + j * 16 + colloc;
    wl[j] = Wlast[col];
    bb[j] = bias[col];
  }
  #pragma unroll
  for (int i = 0; i < 4; ++i) {
    #pragma unroll
    for (int e = 0; e < 4; ++e) {
      int row = rowbase + wr * 64 + i * 16 + rowgrp * 4 + e;
      float tv = tvec[row];
      #pragma unroll
      for (int j = 0; j < 4; ++j) {
        float v = acc[i][j][e] + tv * wl[j] + bb[j];
        if (MODE == 0) v = selu_f(v);
        else           v = fminf(fmaxf(v, -20.f), 20.f);
        int col = colbase + wc * 64 + j * 16 + colloc;
        Yout[(size_t)row * ldy + col] = __float2bfloat16(v);
      }
    }
  }
}

// ---------------- expm: transposed chain, 2 matrices/wave ILP (r11, passing) --
#define WAITLDS asm volatile("s_waitcnt lgkmcnt(0)" ::: "memory")

__device__ __forceinline__ unsigned int bf16r(float x) {
  return (__float_as_uint(x) + 0x8000u) >> 16;
}

__device__ __forceinline__ void d2b_lean(const float (&X)[16], int G, short8 (&bfr)[2]) {
  float rcv[8];
  #pragma unroll
  for (int j = 0; j < 8; ++j) {
    const int hp = j >> 2, tt = j & 3;
    float snd = G ? X[8 * hp + tt] : X[8 * hp + 4 + tt];
    rcv[j] = __shfl_xor(snd, 32);
  }
  #pragma unroll
  for (int h = 0; h < 2; ++h) {
    float r8v[8];
    #pragma unroll
    for (int j2 = 0; j2 < 8; ++j2) {
      if (j2 < 4) r8v[j2] = G ? rcv[4 * h + j2] : X[8 * h + j2];
      else        r8v[j2] = G ? X[8 * h + j2] : rcv[4 * h + j2 - 4];
    }
    union { short8 s8; unsigned int u[4]; } bu;
    #pragma unroll
    for (int j = 0; j < 4; ++j)
      bu.u[j] = bf16r(r8v[2 * j]) | (bf16r(r8v[2 * j + 1]) << 16);
    bfr[h] = bu.s8;
  }
}

__device__ __forceinline__ void d2b_split_lean(const float (&X)[16], int G,
                                               short8 (&bh)[2], short8 (&bl)[2]) {
  float rcv[8];
  #pragma unroll
  for (int j = 0; j < 8; ++j) {
    const int hp = j >> 2, tt = j & 3;
    float snd = G ? X[8 * hp + tt] : X[8 * hp + 4 + tt];
    rcv[j] = __shfl_xor(snd, 32);
  }
  #pragma unroll
  for (int h = 0; h < 2; ++h) {
    float r8v[8];
    #pragma unroll
    for (int j2 = 0; j2 < 8; ++j2) {
      if (j2 < 4) r8v[j2] = G ? rcv[4 * h + j2] : X[8 * h + j2];
      else        r8v[j2] = G ? X[8 * h + j2] : rcv[4 * h + j2 - 4];
    }
    union { short8 s8; unsigned int u[4]; } uh, ul;
    #pragma unroll
    for (int j = 0; j < 4; ++j) {
      unsigned int b0 = __float_as_uint(r8v[2 * j]) & 0xFFFF0000u;
      unsigned int b1 = __float_as_uint(r8v[2 * j + 1]) & 0xFFFF0000u;
      float l0 = r8v[2 * j] - __uint_as_float(b0);
      float l1 = r8v[2 * j + 1] - __uint_as_float(b1);
      uh.u[j] = (b0 >> 16) | b1;
      ul.u[j] = bf16r(l0) | (bf16r(l1) << 16);
    }
    bh[h] = uh.s8;
    bl[h] = ul.s8;
  }
}

union u4s8 { uint4 u4; short8 s8; unsigned int u[4]; };

__global__ __launch_bounds__(256) void expm_ilp2_kernel(
    const __hip_bfloat16* __restrict__ flat,
    const float* __restrict__ q,
    const float* __restrict__ dtp,
    float* __restrict__ out_q,
    float* __restrict__ out_dlogp) {
  __shared__ __align__(16) unsigned int SL[4][2][16][33];
  const int tid = threadIdx.x;
  const int w = tid >> 6, lane = tid & 63;
  const int C = lane & 31, G = lane >> 5;
  const int m0 = blockIdx.x * 8 + w * 2;
  const float dt = dtp[0];

  u4s8 t0[2], t1[2];
  float E[2][16];
  float uu[2];
  int nv[2];

  #pragma unroll
  for (int mm = 0; mm < 2; ++mm) {
    const int m = m0 + mm;
    const uint4* fm = reinterpret_cast<const uint4*>(flat + (size_t)m * 1024);
    uint4 v0 = fm[lane];
    uint4 v1 = fm[lane + 64];
    {
      const int r0 = lane >> 2, kpb = (lane & 3) * 4;
      SL[w][mm][kpb + 0][r0] = v0.x; SL[w][mm][kpb + 1][r0] = v0.y;
      SL[w][mm][kpb + 2][r0] = v0.z; SL[w][mm][kpb + 3][r0] = v0.w;
      SL[w][mm][kpb + 0][r0 + 16] = v1.x; SL[w][mm][kpb + 1][r0 + 16] = v1.y;
      SL[w][mm][kpb + 2][r0 + 16] = v1.z; SL[w][mm][kpb + 3][r0 + 16] = v1.w;
    }
    {
      const char* base = reinterpret_cast<const char*>(flat) + (size_t)m * 2048 + C * 64 + G * 16;
      t0[mm].u4 = *reinterpret_cast<const uint4*>(base);
      t1[mm].u4 = *reinterpret_cast<const uint4*>(base + 32);
    }

    float sa = 0.f;
    #pragma unroll
    for (int i = 0; i < 4; ++i) {
      sa += fabsf(__uint_as_float(t0[mm].u[i] << 16)) + fabsf(__uint_as_float(t0[mm].u[i] & 0xFFFF0000u));
      sa += fabsf(__uint_as_float(t1[mm].u[i] << 16)) + fabsf(__uint_as_float(t1[mm].u[i] & 0xFFFF0000u));
    }
    sa += __shfl_xor(sa, 32);
    float nrm = sa;
    #pragma unroll
    for (int off = 1; off < 32; off <<= 1) nrm = fmaxf(nrm, __shfl_xor(nrm, off));

    int s = 0;
    float anrm = dt * nrm;
    if (anrm > 1.0f) {
      s = (int)ceilf(log2f(anrm));
      s = s < 1 ? 1 : (s > 6 ? 6 : s);
    }
    nv[mm] = 1 << s;
    const float u = dt * exp2f(-(float)s);
    uu[mm] = u;

    unsigned int pt0[4], pt1[4];
    #pragma unroll
    for (int d = 0; d < 4; ++d) {
      pt0[d] = (unsigned int)__shfl_xor((int)t0[mm].u[d], 32);
      pt1[d] = (unsigned int)__shfl_xor((int)t1[mm].u[d], 32);
    }
    float tr = 0.f;
    #pragma unroll
    for (int j = 0; j < 4; ++j) {
      #pragma unroll
      for (int e2 = 0; e2 < 4; ++e2) {
        const int i = 4 * j + e2;
        const int rd = e2 + 8 * j + 4 * G;
        const bool own = ((j & 1) == G);
        unsigned int dwO, dwP;
        if ((e2 >> 1) == 0) {
          dwO = G ? ((j < 2) ? t0[mm].u[2] : t1[mm].u[2]) : ((j < 2) ? t0[mm].u[0] : t1[mm].u[0]);
          dwP = G ? ((j < 2) ? pt0[2] : pt1[2]) : ((j < 2) ? pt0[0] : pt1[0]);
        } else {
          dwO = G ? ((j < 2) ? t0[mm].u[3] : t1[mm].u[3]) : ((j < 2) ? t0[mm].u[1] : t1[mm].u[1]);
          dwP = G ? ((j < 2) ? pt0[3] : pt1[3]) : ((j < 2) ? pt0[1] : pt1[1]);
        }
        unsigned int dw = own ? dwO : dwP;
        unsigned int h16 = (e2 & 1) ? (dw >> 16) : (dw & 0xFFFFu);
        float mv = __uint_as_float(h16 << 16);
        float dI = (rd == C) ? 1.0f : 0.0f;
        E[mm][i] = dI + u * mv;
        tr += dI * mv;
      }
    }
    #pragma unroll
    for (int off = 1; off < 64; off <<= 1) tr += __shfl_xor(tr, off);
    if (lane == 0) out_dlogp[m] = dt * tr;
  }

  WAITLDS;

  short8 Mfr[2][2];
  {
    const unsigned int selpat = (C & 1) ? 0x07060302u : 0x05040100u;
    #pragma unroll
    for (int mm = 0; mm < 2; ++mm) {
      #pragma unroll
      for (int h = 0; h < 2; ++h) {
        unsigned int rr[8];
        #pragma unroll
        for (int e = 0; e < 8; ++e) rr[e] = SL[w][mm][C >> 1][16 * h + 8 * G + e];
        union { short8 s8; unsigned int u[4]; } mu;
        #pragma unroll
        for (int j = 0; j < 4; ++j)
          mu.u[j] = __builtin_amdgcn_perm(rr[2 * j + 1], rr[2 * j], selpat);
        Mfr[mm][h] = mu.s8;
      }
    }
  }

  float Qc[2][16];
  float ck[2];
  #pragma unroll
  for (int mm = 0; mm < 2; ++mm) {
    ck[mm] = uu[mm] * uu[mm] * 0.5f;
    f32x16 acc = {};
    acc = __builtin_amdgcn_mfma_f32_32x32x16_bf16(Mfr[mm][0], t0[mm].s8, acc, 0, 0, 0);
    acc = __builtin_amdgcn_mfma_f32_32x32x16_bf16(Mfr[mm][1], t1[mm].s8, acc, 0, 0, 0);
    #pragma unroll
    for (int i = 0; i < 16; ++i) { Qc[mm][i] = acc[i]; E[mm][i] += ck[mm] * acc[i]; }
  }
  #pragma unroll
  for (int k = 3; k <= 6; ++k) {
    #pragma unroll
    for (int mm = 0; mm < 2; ++mm) {
      short8 bfr[2];
      d2b_lean(Qc[mm], G, bfr);
      f32x16 acc = {};
      acc = __builtin_amdgcn_mfma_f32_32x32x16_bf16(Mfr[mm][0], bfr[0], acc, 0, 0, 0);
      acc = __builtin_amdgcn_mfma_f32_32x32x16_bf16(Mfr[mm][1], bfr[1], acc, 0, 0, 0);
      ck[mm] *= uu[mm] * (1.0f / (float)k);
      #pragma unroll
      for (int i = 0; i < 16; ++i) { Qc[mm][i] = acc[i]; E[mm][i] += ck[mm] * acc[i]; }
    }
  }

  short8 beh[2][2], bel[2][2];
  #pragma unroll
  for (int mm = 0; mm < 2; ++mm)
    d2b_split_lean(E[mm], G, beh[mm], bel[mm]);

  float qv[2];
  qv[0] = q[(size_t)m0 * 32 + C];
  qv[1] = q[(size_t)(m0 + 1) * 32 + C];
  const int nvmax = nv[0] > nv[1] ? nv[0] : nv[1];
  #pragma unroll 1
  for (int it = 0; it < nvmax; ++it) {
    #pragma unroll
    for (int mm = 0; mm < 2; ++mm) {
      unsigned int hb = __float_as_uint(qv[mm]) & 0xFFFF0000u;
      float lof = qv[mm] - __uint_as_float(hb);
      unsigned int pw = (hb >> 16) | (bf16r(lof) << 16);
      short8 vh[2], vl[2];
      #pragma unroll
      for (int h = 0; h < 2; ++h) {
        unsigned int g[8];
        #pragma unroll
        for (int e = 0; e < 8; ++e)
          g[e] = (unsigned int)__shfl((int)pw, 16 * h + 8 * G + e);
        union { short8 s8; unsigned int u[4]; } uh, ul;
        #pragma unroll
        for (int j = 0; j < 4; ++j) {
          uh.u[j] = __builtin_amdgcn_perm(g[2 * j + 1], g[2 * j], 0x05040100u);
          ul.u[j] = __builtin_amdgcn_perm(g[2 * j + 1], g[2 * j], 0x07060302u);
        }
        vh[h] = uh.s8;
        vl[h] = ul.s8;
      }
      f32x16 acc = {};
      acc = __builtin_amdgcn_mfma_f32_32x32x16_bf16(vh[0], beh[mm][0], acc, 0, 0, 0);
      acc = __builtin_amdgcn_mfma_f32_32x32x16_bf16(vh[1], beh[mm][1], acc, 0, 0, 0);
      acc = __builtin_amdgcn_mfma_f32_32x32x16_bf16(vl[0], beh[mm][0], acc, 0, 0, 0);
      acc = __builtin_amdgcn_mfma_f32_32x32x16_bf16(vl[1], beh[mm][1], acc, 0, 0, 0);
      acc = __builtin_amdgcn_mfma_f32_32x32x16_bf16(vh[0], bel[mm][0], acc, 0, 0, 0);
      acc = __builtin_amdgcn_mfma_f32_32x32x16_bf16(vh[1], bel[mm][1], acc, 0, 0, 0);
      qv[mm] = (it < nv[mm]) ? acc[0] : qv[mm];
    }
  }
  if (G == 0) {
    out_q[(size_t)m0 * 32 + C] = qv[0];
    out_q[(size_t)(m0 + 1) * 32 + C] = qv[1];
  }
}

extern "C" void kernel_launch(void* const* d_in, const int* in_sizes, int n_in,
                              void* d_out, int out_size, void* d_ws, size_t ws_size,
                              hipStream_t stream) {
  const float* q    = (const float*)d_in[0];
  const float* p    = (const float*)d_in[1];
  const float* t    = (const float*)d_in[2];
  const float* dt   = (const float*)d_in[3];
  const float* W0   = (const float*)d_in[4];
  const float* b0   = (const float*)d_in[5];
  const float* W1   = (const float*)d_in[6];
  const float* b1   = (const float*)d_in[7];
  const float* W2   = (const float*)d_in[8];
  const float* b2   = (const float*)d_in[9];
  const float* W3   = (const float*)d_in[10];
  const float* b3   = (const float*)d_in[11];
  const float* Wout = (const float*)d_in[12];
  const float* bout = (const float*)d_in[13];

  // ws layout (all bf16 activations)
  __hip_bfloat16* flatb = (__hip_bfloat16*)d_ws;                 // B*1024
  __hip_bfloat16* act1  = flatb + (size_t)BTOT * 1024;           // B*512
  __hip_bfloat16* act2  = act1 + (size_t)BTOT * 512;             // B*512
  __hip_bfloat16* pbf   = act2 + (size_t)BTOT * 512;             // B*32
  __hip_bfloat16* Wt0   = pbf + (size_t)BTOT * 32;
  __hip_bfloat16* Wt1   = Wt0 + 512 * 32;
  __hip_bfloat16* Wt2   = Wt1 + 512 * 512;
  __hip_bfloat16* Wt3   = Wt2 + 512 * 512;
  __hip_bfloat16* WtO   = Wt3 + 512 * 512;

  dim3 blk(256);
  prep_kernel<<<1808, blk, 0, stream>>>(p, pbf, W0, Wt0, W1, Wt1, W2, Wt2,
                                        W3, Wt3, Wout, WtO);

  // r8 grids (bm fastest)
  mlp_mfma_kernel<32, 0><<<dim3(128, 4), blk, 0, stream>>>(
      pbf, 32, 32, t, Wt0, W0 + 32 * 512, b0, act1, 512);
  mlp_mfma_kernel<64, 0><<<dim3(128, 4), blk, 0, stream>>>(
      act1, 512, 512, t, Wt1, W1 + 512 * 512, b1, act2, 512);
  mlp_mfma_kernel<64, 0><<<dim3(128, 4), blk, 0, stream>>>(
      act2, 512, 512, t, Wt2, W2 + 512 * 512, b2, act1, 512);
  mlp_mfma_kernel<64, 0><<<dim3(128, 4), blk, 0, stream>>>(
      act1, 512, 512, t, Wt3, W3 + 512 * 512, b3, act2, 512);
  mlp_mfma_kernel<64, 1><<<dim3(128, 8), blk, 0, stream>>>(
      act2, 512, 512, t, WtO, Wout + 512 * 1024, bout, flatb, 1024);

  float* out_q     = (float*)d_out;
  float* out_dlogp = out_q + (size_t)BTOT * 32;
  expm_ilp2_kernel<<<BTOT / 8, blk, 0, stream>>>(flatb, q, dt, out_q, out_dlogp);
}